// Round 9
// baseline (256.821 us; speedup 1.0000x reference)
//
#include <hip/hip_runtime.h>
#include <cmath>

// Fused Fourier-MLP, R9: pure-f16 MFMA restructure (D = W·X orientation).
// R8 measured: spill fixed (WRITE 16MB), 210us, VALU 39% / Mfma 11% / occ 42%
// -> latency-bound, occupancy capped by 32KB LDS (4 blocks/CU).
// R9 changes:
//  - f16 activation tile (4KB/wave -> 16KB/block -> 8 blocks/CU, cap 100%)
//  - pure-f16 operands, fp32 accum: 52 MFMA/wave (was 104). Error budget OK:
//    R1 (exact fp32) absmax == 0.015625 == every f16 round -> that value is
//    the reference-mismatch floor; f16 error has been invisible under it.
//  - W as A-frag, X as B-frag: X-phase = 4 raw ds_read_b128 (zero cvt VALU),
//    C-phase = packed ds_write_b64 (4 consecutive ch), output = float4 store.
// Tile [32 pts][64 ch] f16, 16B-granule XOR swizzle: phys_g = g ^ (row&7).
// Wave-private tile -> no barriers (same-wave DS ordering, HW-proven R2-R8).
// Fragment k-map (both operands, HW-validated R2): slot j, group g, chunk c
// <-> k = 32c + 8g + j. C-layout (HW-validated): col = l15, row = 4g + r.

typedef _Float16 half8 __attribute__((ext_vector_type(8)));
typedef _Float16 half4v __attribute__((ext_vector_type(4)));
typedef float float4v __attribute__((ext_vector_type(4)));

#define PI_F 3.14159265358979323846f

__device__ __forceinline__ float4v mfma16(half8 a, half8 b, float4v c) {
    return __builtin_amdgcn_mfma_f32_16x16x32_f16(a, b, c, 0, 0, 0);
}

// MODE 0: W0 [64][51] (predicated k<51)   MODE 1: dense [64][64]
// MODE 2: W3 [4][64] final -> global float4 store
template <int MODE>
__device__ __forceinline__ void layer(const float* __restrict__ W,
                                      const float* __restrict__ bias,
                                      _Float16* __restrict__ hb,
                                      float* __restrict__ outp,
                                      long long wbase, int lane, long long n)
{
    const int l15 = lane & 15;
    const int g   = lane >> 4;

    // ---- X-phase: load ALL activation B-frags first (in-place safety:
    // every read precedes every write in program order; same-wave DS is
    // ordered). B-frag slot j = ch 32c+8g+j = f16 granule (4c+g), raw b128.
    half8 X[2][2];
#pragma unroll
    for (int ptt = 0; ptt < 2; ++ptt)
#pragma unroll
        for (int c = 0; c < 2; ++c) {
            const int row = 16 * ptt + l15;
            X[ptt][c] = *(const half8*)&hb[row * 64 + (((4 * c + g) ^ (row & 7)) << 3)];
        }

    constexpr int NCHT = (MODE == 2) ? 1 : 4;
#pragma unroll
    for (int cht = 0; cht < NCHT; ++cht) {
        // ---- W-phase: A-frag, lane row = out-channel 16cht+l15, k = 32c+8g+j
        half8 Wf[2];
        if constexpr (MODE == 1) {
            const int jr = 16 * cht + l15;
#pragma unroll
            for (int c = 0; c < 2; ++c) {
                const float4v w0 = *(const float4v*)(W + jr * 64 + 32 * c + 8 * g);
                const float4v w1 = *(const float4v*)(W + jr * 64 + 32 * c + 8 * g + 4);
#pragma unroll
                for (int j = 0; j < 4; ++j) {
                    Wf[c][j]     = (_Float16)w0[j];
                    Wf[c][4 + j] = (_Float16)w1[j];
                }
            }
        } else if constexpr (MODE == 0) {
            const int jr = 16 * cht + l15;                  // stride 51
#pragma unroll
            for (int c = 0; c < 2; ++c)
#pragma unroll
                for (int j = 0; j < 8; ++j) {
                    const int k = 32 * c + 8 * g + j;
                    Wf[c][j] = (k < 51) ? (_Float16)W[jr * 51 + k] : (_Float16)0.0f;
                }
        } else {                                            // MODE 2: W3 [4][64]
#pragma unroll
            for (int c = 0; c < 2; ++c) {
                if (l15 < 4) {
                    const float4v w0 = *(const float4v*)(W + l15 * 64 + 32 * c + 8 * g);
                    const float4v w1 = *(const float4v*)(W + l15 * 64 + 32 * c + 8 * g + 4);
#pragma unroll
                    for (int j = 0; j < 4; ++j) {
                        Wf[c][j]     = (_Float16)w0[j];
                        Wf[c][4 + j] = (_Float16)w1[j];
                    }
                } else {
#pragma unroll
                    for (int j = 0; j < 8; ++j) Wf[c][j] = (_Float16)0.0f;
                }
            }
        }

        // ---- bias C-init: lane's D rows are ch = 16cht + 4g + r, r = 0..3
        float4v binit;
        if constexpr (MODE == 2) {
            if (g == 0) binit = *(const float4v*)bias;      // b3[0..3]
            else        binit = float4v{0.f, 0.f, 0.f, 0.f};
        } else {
            binit = *(const float4v*)(bias + 16 * cht + 4 * g);   // 16B aligned
        }

#pragma unroll
        for (int ptt = 0; ptt < 2; ++ptt) {
            float4v acc = binit;
            acc = mfma16(Wf[0], X[ptt][0], acc);
            acc = mfma16(Wf[1], X[ptt][1], acc);

            if constexpr (MODE == 2) {
                if (g == 0) {                               // rows r = ch 0..3
                    const long long p = wbase + 16 * ptt + l15;
                    if (p < n) *(float4v*)(outp + p * 4) = acc;   // coalesced
                }
            } else {
                // relu + pack 4 consecutive ch -> ds_write_b64
                half4v hv;
#pragma unroll
                for (int r = 0; r < 4; ++r) hv[r] = (_Float16)fmaxf(acc[r], 0.0f);
                const int row  = 16 * ptt + l15;            // point row
                const int ch0  = 16 * cht + 4 * g;
                const int gran = ch0 >> 3;                  // 2cht + (g>>1)
                *(half4v*)&hb[row * 64 + ((gran ^ (row & 7)) << 3) + (ch0 & 7)] = hv;
            }
        }
    }
}

__global__ __launch_bounds__(256)
void fused_mlp_r9(const float* __restrict__ x,
                  const float* __restrict__ W0, const float* __restrict__ b0,
                  const float* __restrict__ W1, const float* __restrict__ b1,
                  const float* __restrict__ W2, const float* __restrict__ b2,
                  const float* __restrict__ W3, const float* __restrict__ b3,
                  float* __restrict__ out, long long n)
{
    __shared__ _Float16 hbuf[4][32 * 64];                  // 16 KB: 4 KB/wave
    const int tid  = threadIdx.x;
    const int wave = tid >> 6;
    const int lane = tid & 63;
    _Float16* hb = hbuf[wave];

    const long long wbase = (long long)blockIdx.x * 128 + wave * 32;

    // ---- encoding: lane pair (l, l+32) both compute point (wbase + (l&31));
    // half-wave 0 writes ch 0..31 (granules 0..3), half-wave 1 ch 32..63
    // (granules 4..7). All e[] indices compile-time (rule #20, R8-proven).
    {
        const int row = lane & 31, rs7 = row & 7;
        long long p = wbase + row;
        if (p > n - 1) p = n - 1;
        const float xc[3] = {x[3 * p + 0], x[3 * p + 1], x[3 * p + 2]};

        float s[3][8], c[3][8];
#pragma unroll
        for (int ch = 0; ch < 3; ++ch) {
            sincosf(PI_F * xc[ch], &s[ch][0], &c[ch][0]);   // seed (arg <= pi)
#pragma unroll
            for (int f = 1; f < 8; ++f) {                    // double-angle
                const float sp = s[ch][f - 1], cp = c[ch][f - 1];
                s[ch][f] = 2.0f * sp * cp;
                c[ch][f] = fmaf(2.0f * cp, cp, -1.0f);
            }
        }

        float e[64];
#pragma unroll
        for (int k = 0; k < 64; ++k) e[k] = 0.0f;
        e[0] = xc[0]; e[1] = xc[1]; e[2] = xc[2];
#pragma unroll
        for (int ch = 0; ch < 3; ++ch)
#pragma unroll
            for (int f = 0; f < 8; ++f) {
                e[3  + ch * 8 + f] = s[ch][f];
                e[27 + ch * 8 + f] = c[ch][f];
            }

        if (lane < 32) {
#pragma unroll
            for (int t = 0; t < 4; ++t) {                    // granules 0..3
                half8 v;
#pragma unroll
                for (int j = 0; j < 8; ++j) v[j] = (_Float16)e[8 * t + j];
                *(half8*)&hb[row * 64 + ((t ^ rs7) << 3)] = v;
            }
        } else {
#pragma unroll
            for (int t = 0; t < 4; ++t) {                    // granules 4..7
                half8 v;
#pragma unroll
                for (int j = 0; j < 8; ++j) v[j] = (_Float16)e[32 + 8 * t + j];
                *(half8*)&hb[row * 64 + (((4 + t) ^ rs7) << 3)] = v;
            }
        }
    }
    // no barrier: tile is wave-private; same-wave DS ops are ordered

    layer<0>(W0, b0, hb, nullptr, wbase, lane, n);
    layer<1>(W1, b1, hb, nullptr, wbase, lane, n);
    layer<1>(W2, b2, hb, nullptr, wbase, lane, n);
    layer<2>(W3, b3, hb, out,     wbase, lane, n);
}

extern "C" void kernel_launch(void* const* d_in, const int* in_sizes, int n_in,
                              void* d_out, int out_size, void* d_ws, size_t ws_size,
                              hipStream_t stream)
{
    const float* x  = (const float*)d_in[0];
    const float* W0 = (const float*)d_in[1];
    const float* b0 = (const float*)d_in[2];
    const float* W1 = (const float*)d_in[3];
    const float* b1 = (const float*)d_in[4];
    const float* W2 = (const float*)d_in[5];
    const float* b2 = (const float*)d_in[6];
    const float* W3 = (const float*)d_in[7];
    const float* b3 = (const float*)d_in[8];
    float* out = (float*)d_out;

    const long long n = in_sizes[0] / 3;                   // 1<<20 points
    const int grid = (int)((n + 127) / 128);               // 32 pts/wave, 4 waves
    fused_mlp_r9<<<grid, 256, 0, stream>>>(x, W0, b0, W1, b1, W2, b2, W3, b3, out, n);
}